// Round 3
// baseline (179.734 us; speedup 1.0000x reference)
//
#include <hip/hip_runtime.h>
#include <hip/hip_bf16.h>

// Embedding gather: out[t, :] = weight[ids[t], :]
// B*S = 8192 tokens, D = 1024 fp32 per row (4 KiB).
//
// R2 (= R1 with compile fix): 8 tokens per block for memory-level parallelism.
//   - 8 wave-uniform index loads (scalar path)
//   - 8 independent 16B gathers in flight per thread (ILP=8)
//   - 8 nontemporal 16B stores (out is write-once; don't evict the
//     L3-resident 128 MiB weight table)
// Fix vs R1: __builtin_nontemporal_store needs a clang ext_vector_type,
// not HIP's struct float4.

#define D_DIM 1024
#define TOK_PER_BLK 8

typedef float vfloat4 __attribute__((ext_vector_type(4)));

__global__ __launch_bounds__(256) void embed_gather_kernel(
    const int* __restrict__ ids,
    const float* __restrict__ weight,
    float* __restrict__ out,
    int n_tokens)
{
    const int t0   = blockIdx.x * TOK_PER_BLK;
    const int lane = threadIdx.x;  // 0..255, one 16B chunk per row each

    if (t0 + TOK_PER_BLK <= n_tokens) {
        // Fast path: full group of 8 tokens.
        int rows[TOK_PER_BLK];
#pragma unroll
        for (int k = 0; k < TOK_PER_BLK; ++k)
            rows[k] = ids[t0 + k];          // wave-uniform -> s_load

        vfloat4 v[TOK_PER_BLK];
#pragma unroll
        for (int k = 0; k < TOK_PER_BLK; ++k) {
            const vfloat4* src =
                reinterpret_cast<const vfloat4*>(weight + (size_t)rows[k] * D_DIM);
            v[k] = src[lane];               // 8 loads in flight
        }

#pragma unroll
        for (int k = 0; k < TOK_PER_BLK; ++k) {
            vfloat4* dst =
                reinterpret_cast<vfloat4*>(out + (size_t)(t0 + k) * D_DIM);
            __builtin_nontemporal_store(v[k], &dst[lane]);
        }
    } else {
        // Tail (not hit at B*S=8192, kept for safety).
        for (int k = 0; k < TOK_PER_BLK; ++k) {
            const int t = t0 + k;
            if (t >= n_tokens) break;
            const int row = ids[t];
            const vfloat4* src =
                reinterpret_cast<const vfloat4*>(weight + (size_t)row * D_DIM);
            vfloat4* dst =
                reinterpret_cast<vfloat4*>(out + (size_t)t * D_DIM);
            __builtin_nontemporal_store(src[lane], &dst[lane]);
        }
    }
}

extern "C" void kernel_launch(void* const* d_in, const int* in_sizes, int n_in,
                              void* d_out, int out_size, void* d_ws, size_t ws_size,
                              hipStream_t stream) {
    const int*   ids    = (const int*)d_in[0];     // token_ids [B,S] int32
    const float* weight = (const float*)d_in[1];   // [VOCAB, D] fp32
    float*       out    = (float*)d_out;           // [B,S,D] fp32

    const int n_tokens = in_sizes[0];              // B*S = 8192
    const int n_blocks = (n_tokens + TOK_PER_BLK - 1) / TOK_PER_BLK;  // 1024

    embed_gather_kernel<<<n_blocks, 256, 0, stream>>>(ids, weight, out, n_tokens);
}